// Round 2
// baseline (1907.704 us; speedup 1.0000x reference)
//
#include <hip/hip_runtime.h>
#include <math.h>

#define BB 48
#define TT 32
#define DD 1024
#define SZ 512
#define NCELLS 528  // 32*33/2

__device__ __forceinline__ int off_of(int k) { return TT * k - (k * (k - 1)) / 2; }

// ---------------------------------------------------------------------------
// Leaf GEMM: chart_h[:, :32] = relu(x @ w_leaf + b_leaf)  (pre-normalization)
// (1536 x 1024) x (1024 x 512), tile 32x64, BK=32, grid (8, 48), 256 thr.
// ---------------------------------------------------------------------------
__global__ __launch_bounds__(256) void leaf_gemm(
    const float* __restrict__ x, const float* __restrict__ w_leaf,
    const float* __restrict__ b_leaf, float* __restrict__ chart_h)
{
    __shared__ float Xs[32][36];   // k-major (transposed)
    __shared__ float Bs[32][64];
    const int t = threadIdx.x;
    const int col0 = blockIdx.x * 64;
    const int row0 = blockIdx.y * 32;

    const int ar = t >> 3;          // 0..31 (row within tile)
    const int ak = (t & 7) * 4;     // k sub-offset
    const float* aptr = x + (size_t)(row0 + ar) * DD + ak;

    const int bslot = t & 15;       // 16 float4 slots over 64 cols
    const int brow = t >> 4;        // 0..15
    const float* bptr = w_leaf + (size_t)brow * SZ + col0 + bslot * 4;

    const int ty = t >> 4, tx = t & 15;   // rows ty*2..+1, cols tx*4..+3
    float acc[2][4];
    #pragma unroll
    for (int i = 0; i < 2; ++i)
        #pragma unroll
        for (int j = 0; j < 4; ++j) acc[i][j] = 0.f;

    for (int k0 = 0; k0 < DD; k0 += 32) {
        __syncthreads();
        {
            float4 v = *(const float4*)(aptr + k0);
            Xs[ak + 0][ar] = v.x; Xs[ak + 1][ar] = v.y;
            Xs[ak + 2][ar] = v.z; Xs[ak + 3][ar] = v.w;
        }
        #pragma unroll
        for (int p = 0; p < 2; ++p) {
            *(float4*)&Bs[brow + p * 16][bslot * 4] =
                *(const float4*)(bptr + (size_t)(k0 + p * 16) * SZ);
        }
        __syncthreads();
        #pragma unroll
        for (int k = 0; k < 32; ++k) {
            float2 a2 = *(const float2*)&Xs[k][ty * 2];
            float4 b4 = *(const float4*)&Bs[k][tx * 4];
            float av[2] = {a2.x, a2.y};
            float bv[4] = {b4.x, b4.y, b4.z, b4.w};
            #pragma unroll
            for (int i = 0; i < 2; ++i)
                #pragma unroll
                for (int j = 0; j < 4; ++j)
                    acc[i][j] = fmaf(av[i], bv[j], acc[i][j]);
        }
    }

    float4 bc = *(const float4*)&b_leaf[col0 + tx * 4];
    #pragma unroll
    for (int i = 0; i < 2; ++i) {
        int g = row0 + ty * 2 + i;
        int b = g >> 5, pos = g & 31;
        float4 v;
        v.x = fmaxf(acc[i][0] + bc.x, 0.f);
        v.y = fmaxf(acc[i][1] + bc.y, 0.f);
        v.z = fmaxf(acc[i][2] + bc.z, 0.f);
        v.w = fmaxf(acc[i][3] + bc.w, 0.f);
        *(float4*)&chart_h[((size_t)b * NCELLS + pos) * SZ + col0 + tx * 4] = v;
    }
}

// In-place row normalization of the 1536 leaf cells + Sarr=0.
__global__ __launch_bounds__(256) void leaf_norm(
    float* __restrict__ chart_h, float* __restrict__ Sarr)
{
    const int r = blockIdx.x;               // 0..1535
    const int b = r >> 5, pos = r & 31;
    const size_t base = ((size_t)b * NCELLS + pos) * SZ;
    const int t = threadIdx.x, lane = t & 63, wave = t >> 6;
    __shared__ float red[4];

    float2 v = *(const float2*)&chart_h[base + 2 * t];
    float sq = v.x * v.x + v.y * v.y;
    #pragma unroll
    for (int o = 32; o; o >>= 1) sq += __shfl_xor(sq, o);
    if (lane == 0) red[wave] = sq;
    __syncthreads();
    float nrm = sqrtf(red[0] + red[1] + red[2] + red[3]);
    float inv = 1.f / fmaxf(nrm, 1e-12f);
    v.x *= inv; v.y *= inv;
    *(float2*)&chart_h[base + 2 * t] = v;
    if (t == 0) Sarr[(size_t)b * NCELLS + pos] = 0.f;
}

// ---------------------------------------------------------------------------
// Transform: (B*L x 512) x (512 x 1536) fp32 GEMM, tile 64x128, BK=32.
// grid = (12 col-tiles, ceil(B*L/64)), 256 threads, 4x8 acc/thread.
// ct>>2 selects W segment/output: 0->A (w_comp top), 1->C (bottom), 2->U (s_bil)
// ---------------------------------------------------------------------------
__global__ __launch_bounds__(256) void transform_kernel(
    const float* __restrict__ chart_h, const float* __restrict__ w_comp,
    const float* __restrict__ s_bil,
    float* __restrict__ Ao, float* __restrict__ Co, float* __restrict__ Uo,
    int level)
{
    __shared__ float As[32][68];   // k-major (transposed), pad 4
    __shared__ float Bs[32][128];
    const int L = TT - level;
    const int rows = BB * L;
    const int off = off_of(level);
    const int ct = blockIdx.x;     // 0..11
    const int rt = blockIdx.y;
    const int col0 = (ct & 3) * 128;

    const float* W; float* Out;
    int sel = ct >> 2;
    if (sel == 0)      { W = w_comp;                   Out = Ao; }
    else if (sel == 1) { W = w_comp + (size_t)SZ * SZ; Out = Co; }
    else               { W = s_bil;                    Out = Uo; }

    const int t = threadIdx.x;
    const int ar = t >> 3;          // 0..31
    const int ak = (t & 7) * 4;
    const float* aptr[2];
    #pragma unroll
    for (int p = 0; p < 2; ++p) {
        int g = rt * 64 + ar + p * 32;
        if (g < rows) {
            int b = g / L, pos = g % L;
            aptr[p] = chart_h + ((size_t)b * NCELLS + off + pos) * SZ + ak;
        } else aptr[p] = nullptr;
    }
    const int bslot = t & 31;       // 32 float4 slots over 128 cols
    const int brow = t >> 5;        // 0..7
    const float* bptr = W + (size_t)brow * SZ + col0 + bslot * 4;

    const int ty = t >> 4, tx = t & 15;   // rows ty*4..+3; cols tx*4 & 64+tx*4
    float acc[4][8];
    #pragma unroll
    for (int i = 0; i < 4; ++i)
        #pragma unroll
        for (int j = 0; j < 8; ++j) acc[i][j] = 0.f;

    for (int k0 = 0; k0 < SZ; k0 += 32) {
        __syncthreads();
        #pragma unroll
        for (int p = 0; p < 2; ++p) {
            float4 v = make_float4(0.f, 0.f, 0.f, 0.f);
            if (aptr[p]) v = *(const float4*)(aptr[p] + k0);
            As[ak + 0][ar + p * 32] = v.x;
            As[ak + 1][ar + p * 32] = v.y;
            As[ak + 2][ar + p * 32] = v.z;
            As[ak + 3][ar + p * 32] = v.w;
        }
        #pragma unroll
        for (int p = 0; p < 4; ++p) {
            *(float4*)&Bs[brow + p * 8][bslot * 4] =
                *(const float4*)(bptr + (size_t)(k0 + p * 8) * SZ);
        }
        __syncthreads();
        #pragma unroll
        for (int k = 0; k < 32; ++k) {
            float4 a4 = *(const float4*)&As[k][ty * 4];
            float4 b0 = *(const float4*)&Bs[k][tx * 4];
            float4 b1 = *(const float4*)&Bs[k][64 + tx * 4];
            float av[4] = {a4.x, a4.y, a4.z, a4.w};
            float b0v[4] = {b0.x, b0.y, b0.z, b0.w};
            float b1v[4] = {b1.x, b1.y, b1.z, b1.w};
            #pragma unroll
            for (int i = 0; i < 4; ++i) {
                #pragma unroll
                for (int j = 0; j < 4; ++j) {
                    acc[i][j]     = fmaf(av[i], b0v[j], acc[i][j]);
                    acc[i][j + 4] = fmaf(av[i], b1v[j], acc[i][j + 4]);
                }
            }
        }
    }

    #pragma unroll
    for (int i = 0; i < 4; ++i) {
        int g = rt * 64 + ty * 4 + i;
        if (g < rows) {
            int b = g / L, pos = g % L;
            size_t base = ((size_t)b * NCELLS + off + pos) * SZ + col0;
            *(float4*)&Out[base + tx * 4] =
                make_float4(acc[i][0], acc[i][1], acc[i][2], acc[i][3]);
            *(float4*)&Out[base + 64 + tx * 4] =
                make_float4(acc[i][4], acc[i][5], acc[i][6], acc[i][7]);
        }
    }
}

// ---------------------------------------------------------------------------
// Combine: one block per (b, pos) at `level`.
// ---------------------------------------------------------------------------
__global__ __launch_bounds__(256) void combine_kernel(
    float* __restrict__ chart_h,
    const float* __restrict__ Aarr, const float* __restrict__ Carr,
    const float* __restrict__ Uarr, float* __restrict__ Sarr,
    const float* __restrict__ b_comp, int level)
{
    const int L = TT - level, N = level;
    const int bid = blockIdx.x;
    const int b = bid / L, pos = bid % L;
    const int off = off_of(level);

    __shared__ float s_lds[32], p_lds[32];
    __shared__ int lcell[32], rcell[32];
    __shared__ float red[4];

    const int t = threadIdx.x, lane = t & 63, wave = t >> 6;

    if (t < N) {
        lcell[t] = off_of(t) + pos;
        rcell[t] = off_of(level - t - 1) + pos + t + 1;
    }
    __syncthreads();

    // phase 1: bilinear scores  s_n = u_l . h_r + s_l + s_r
    for (int n = wave; n < N; n += 4) {
        const float* u  = Uarr    + ((size_t)b * NCELLS + lcell[n]) * SZ;
        const float* hr = chart_h + ((size_t)b * NCELLS + rcell[n]) * SZ;
        float d = 0.f;
        #pragma unroll
        for (int jj = 0; jj < 4; ++jj) {
            int j = lane * 2 + jj * 128;
            float2 uv = *(const float2*)&u[j];
            float2 hv = *(const float2*)&hr[j];
            d = fmaf(uv.x, hv.x, d);
            d = fmaf(uv.y, hv.y, d);
        }
        #pragma unroll
        for (int o = 32; o; o >>= 1) d += __shfl_xor(d, o);
        if (lane == 0)
            s_lds[n] = d + Sarr[(size_t)b * NCELLS + lcell[n]]
                         + Sarr[(size_t)b * NCELLS + rcell[n]];
    }
    __syncthreads();

    // phase 1b: softmax over N (wave 0) + sbar
    if (wave == 0) {
        float sv = (lane < N) ? s_lds[lane] : -INFINITY;
        float m = sv;
        #pragma unroll
        for (int o = 32; o; o >>= 1) m = fmaxf(m, __shfl_xor(m, o));
        float e = (lane < N) ? expf(sv - m) : 0.f;
        float sum = e;
        #pragma unroll
        for (int o = 32; o; o >>= 1) sum += __shfl_xor(sum, o);
        float p = e / sum;
        if (lane < N) p_lds[lane] = p;
        float sb = (lane < N) ? sv * p : 0.f;
        #pragma unroll
        for (int o = 32; o; o >>= 1) sb += __shfl_xor(sb, o);
        if (lane == 0) Sarr[(size_t)b * NCELLS + off + pos] = sb;
    }
    __syncthreads();

    // phase 2: weighted relu-compose (float2 per thread)
    const int j = 2 * t;
    float2 bc = *(const float2*)&b_comp[j];
    float hx = 0.f, hy = 0.f;
    for (int n = 0; n < N; ++n) {
        size_t lbase = ((size_t)b * NCELLS + lcell[n]) * SZ;
        size_t rbase = ((size_t)b * NCELLS + rcell[n]) * SZ;
        float p = p_lds[n];
        float2 va = *(const float2*)&Aarr[lbase + j];
        float2 vc = *(const float2*)&Carr[rbase + j];
        hx = fmaf(p, fmaxf(va.x + vc.x + bc.x, 0.f), hx);
        hy = fmaf(p, fmaxf(va.y + vc.y + bc.y, 0.f), hy);
    }

    float sq = hx * hx + hy * hy;
    #pragma unroll
    for (int o = 32; o; o >>= 1) sq += __shfl_xor(sq, o);
    if (lane == 0) red[wave] = sq;
    __syncthreads();
    float nrm = sqrtf(red[0] + red[1] + red[2] + red[3]);
    float inv = 1.f / fmaxf(nrm, 1e-12f);
    size_t obase = ((size_t)b * NCELLS + off + pos) * SZ;
    *(float2*)&chart_h[obase + j] = make_float2(hx * inv, hy * inv);
}

// ---------------------------------------------------------------------------
extern "C" void kernel_launch(void* const* d_in, const int* in_sizes, int n_in,
                              void* d_out, int out_size, void* d_ws, size_t ws_size,
                              hipStream_t stream)
{
    const float* x      = (const float*)d_in[0];
    const float* w_leaf = (const float*)d_in[1];
    const float* b_leaf = (const float*)d_in[2];
    const float* w_comp = (const float*)d_in[3];
    const float* b_comp = (const float*)d_in[4];
    const float* s_bil  = (const float*)d_in[5];
    float* chart_h = (float*)d_out;

    float* ws   = (float*)d_ws;
    const size_t cellsz = (size_t)BB * NCELLS * SZ;
    float* Aarr = ws;
    float* Carr = Aarr + cellsz;
    float* Uarr = Carr + cellsz;
    float* Sarr = Uarr + cellsz;

    leaf_gemm<<<dim3(8, 48), 256, 0, stream>>>(x, w_leaf, b_leaf, chart_h);
    leaf_norm<<<BB * TT, 256, 0, stream>>>(chart_h, Sarr);

    {   // transforms for the leaf level: rows = 1536
        transform_kernel<<<dim3(12, 24), 256, 0, stream>>>(
            chart_h, w_comp, s_bil, Aarr, Carr, Uarr, 0);
    }

    for (int level = 1; level < TT; ++level) {
        int L = TT - level;
        combine_kernel<<<BB * L, 256, 0, stream>>>(
            chart_h, Aarr, Carr, Uarr, Sarr, b_comp, level);
        if (level < TT - 1) {
            int rows = BB * L;
            transform_kernel<<<dim3(12, (rows + 63) / 64), 256, 0, stream>>>(
                chart_h, w_comp, s_bil, Aarr, Carr, Uarr, level);
        }
    }
}